// Round 1
// baseline (3841.519 us; speedup 1.0000x reference)
//
#include <hip/hip_runtime.h>
#include <math.h>

#define HH 180
#define WW 240
#define T_AGGC 3
#define NBC 4
#define BBC (NBC * T_AGGC)          // 12
#define M_EVC 32
#define ROWS (BBC * 2 * HH * WW)    // 1,036,800
#define MLPH 20
#define RNNH 20
#define LRELU_SLOPE 0.1f

__device__ __forceinline__ float lrelu(float x) { return x > 0.0f ? x : LRELU_SLOPE * x; }
__device__ __forceinline__ float sigm(float x)  { return 1.0f / (1.0f + __expf(-x)); }
__device__ __forceinline__ float ftanh(float x) { return 1.0f - 2.0f / (__expf(2.0f * x) + 1.0f); }

// ---------------- Kernel 1: per-event MLP + scatter ----------------
__global__ __launch_bounds__(256) void ev_mlp_scatter(
    const float* __restrict__ ev, int n,
    const float* __restrict__ W1, const float* __restrict__ b1,
    const float* __restrict__ W2, const float* __restrict__ b2,
    const float* __restrict__ W3, const float* __restrict__ b3,
    float* __restrict__ vox, unsigned int* __restrict__ mask,
    float* __restrict__ rsum)
{
    __shared__ __align__(16) float sW2[MLPH * MLPH];
    __shared__ float sW1[MLPH], sb1[MLPH], sb2[MLPH], sW3[MLPH];
    __shared__ float sb3;
    int tid = threadIdx.x;
    for (int i = tid; i < MLPH * MLPH; i += blockDim.x) sW2[i] = W2[i];
    if (tid < MLPH) { sW1[tid] = W1[tid]; sb1[tid] = b1[tid]; sb2[tid] = b2[tid]; sW3[tid] = W3[tid]; }
    if (tid == 0) sb3 = b3[0];
    __syncthreads();

    int i = blockIdx.x * blockDim.x + tid;
    if (i >= n) return;
    const float* e = ev + (size_t)i * 7;
    float t = e[3];

    float h1[MLPH];
#pragma unroll
    for (int k = 0; k < MLPH; k++) h1[k] = lrelu(fmaf(t, sW1[k], sb1[k]));

    float val = sb3;
#pragma unroll
    for (int j = 0; j < MLPH; j++) {
        float a = sb2[j];
        const float4* wr = (const float4*)&sW2[j * MLPH];
#pragma unroll
        for (int k4 = 0; k4 < MLPH / 4; k4++) {
            float4 w = wr[k4];
            a = fmaf(h1[k4 * 4 + 0], w.x, a);
            a = fmaf(h1[k4 * 4 + 1], w.y, a);
            a = fmaf(h1[k4 * 4 + 2], w.z, a);
            a = fmaf(h1[k4 * 4 + 3], w.w, a);
        }
        val = fmaf(lrelu(a), sW3[j], val);
    }

    int xi = (int)e[0], yi = (int)e[1], pi = (int)e[2];
    int ipi = (int)e[4], ti = (int)e[5], bi = (int)e[6];
    int row = xi + WW * yi + WW * HH * pi + 2 * WW * HH * (bi * T_AGGC + ti);
    int pos = ipi - 1;
    vox[(size_t)row * M_EVC + pos] = val;
    if (val != 0.0f) {                       // matches (vox != 0) semantics
        atomicOr(&mask[row], 1u << pos);
        atomicAdd(&rsum[row], val);
    }
}

// ---------------- Kernel 2: per-row LSTM ----------------
__global__ __launch_bounds__(256) void row_lstm(
    const unsigned int* __restrict__ mask, const float* __restrict__ rsum,
    const float* __restrict__ vox,
    const float* __restrict__ rW1, const float* __restrict__ rb1,
    const float* __restrict__ Wih, const float* __restrict__ Whh,
    const float* __restrict__ bih, const float* __restrict__ bhh,
    const float* __restrict__ rW2, const float* __restrict__ rb2,
    float* __restrict__ out)
{
    __shared__ __align__(16) float sWhh[4 * RNNH * RNNH];   // 1600 floats
    __shared__ float sA[4 * RNNH], sC[4 * RNNH], sW2[RNNH];
    __shared__ float sb2o;
    int tid = threadIdx.x;
    for (int i = tid; i < 4 * RNNH * RNNH; i += blockDim.x) sWhh[i] = Whh[i];
    if (tid < 4 * RNNH) {
        float a = 0.0f, c = bih[tid] + bhh[tid];
        for (int k = 0; k < RNNH; k++) {
            float w = Wih[tid * RNNH + k];
            a = fmaf(rW1[k], w, a);
            c = fmaf(rb1[k], w, c);
        }
        sA[tid] = a; sC[tid] = c;
    }
    if (tid < RNNH) sW2[tid] = rW2[tid];
    if (tid == 0) sb2o = rb2[0];
    __syncthreads();

    int row = blockIdx.x * blockDim.x + tid;
    if (row >= ROWS) return;

    float s = rsum[row];
    if (s == 0.0f) { out[row] = 0.0f; return; }

    unsigned int m = mask[row];
    int len = __popc(m);
    const float* vrow = vox + (size_t)row * M_EVC;

    float h[RNNH], c[RNNH];

    // ---- step 0 (h = c = 0): gates = x*A + C, sigma(f)*c_prev == 0 ----
    {
        float x0 = (m & 1u) ? vrow[0] : 0.0f;
#pragma unroll
        for (int u = 0; u < RNNH; u++) {
            float gi = fmaf(x0, sA[u],            sC[u]);
            float gg = fmaf(x0, sA[u + 2 * RNNH], sC[u + 2 * RNNH]);
            float go = fmaf(x0, sA[u + 3 * RNNH], sC[u + 3 * RNNH]);
            float cn = sigm(gi) * ftanh(gg);
            c[u] = cn;
            h[u] = sigm(go) * ftanh(cn);
        }
    }

    // ---- steps 1..len-1 ----
    for (int j = 1; j < len; j++) {
        float xj = ((m >> j) & 1u) ? vrow[j] : 0.0f;
        float hn[RNNH];
#pragma unroll
        for (int u = 0; u < RNNH; u++) {
            float gacc[4];
#pragma unroll
            for (int g4 = 0; g4 < 4; g4++) {
                float acc = fmaf(xj, sA[u + g4 * RNNH], sC[u + g4 * RNNH]);
                const float4* wr = (const float4*)&sWhh[(u + g4 * RNNH) * RNNH];
#pragma unroll
                for (int k4 = 0; k4 < RNNH / 4; k4++) {
                    float4 w = wr[k4];
                    acc = fmaf(h[k4 * 4 + 0], w.x, acc);
                    acc = fmaf(h[k4 * 4 + 1], w.y, acc);
                    acc = fmaf(h[k4 * 4 + 2], w.z, acc);
                    acc = fmaf(h[k4 * 4 + 3], w.w, acc);
                }
                gacc[g4] = acc;
            }
            float cn = sigm(gacc[1]) * c[u] + sigm(gacc[0]) * ftanh(gacc[2]);
            c[u] = cn;
            hn[u] = sigm(gacc[3]) * ftanh(cn);
        }
#pragma unroll
        for (int u = 0; u < RNNH; u++) h[u] = hn[u];
    }

    float o = sb2o;
#pragma unroll
    for (int u = 0; u < RNNH; u++) o = fmaf(h[u], sW2[u], o);
    out[row] = o;
}

extern "C" void kernel_launch(void* const* d_in, const int* in_sizes, int n_in,
                              void* d_out, int out_size, void* d_ws, size_t ws_size,
                              hipStream_t stream) {
    const float* ev     = (const float*)d_in[0];
    const float* mlp_W1 = (const float*)d_in[1];
    const float* mlp_b1 = (const float*)d_in[2];
    const float* mlp_W2 = (const float*)d_in[3];
    const float* mlp_b2 = (const float*)d_in[4];
    const float* mlp_W3 = (const float*)d_in[5];
    const float* mlp_b3 = (const float*)d_in[6];
    const float* rnn_W1 = (const float*)d_in[7];
    const float* rnn_b1 = (const float*)d_in[8];
    const float* W_ih   = (const float*)d_in[9];
    const float* W_hh   = (const float*)d_in[10];
    const float* b_ih   = (const float*)d_in[11];
    const float* b_hh   = (const float*)d_in[12];
    const float* rnn_W2 = (const float*)d_in[13];
    const float* rnn_b2 = (const float*)d_in[14];

    int n = in_sizes[0] / 7;
    float* outp = (float*)d_out;

    unsigned char* ws = (unsigned char*)d_ws;
    unsigned int* mask = (unsigned int*)ws;                    // ROWS u32
    float*        rsum = (float*)(ws + (size_t)ROWS * 4);      // ROWS f32
    float*        vox  = (float*)(ws + (size_t)ROWS * 8);      // ROWS*32 f32 (no zeroing needed; reads gated by mask)

    hipMemsetAsync(mask, 0, (size_t)ROWS * 8, stream);

    int blk = 256;
    int grid1 = (n + blk - 1) / blk;
    ev_mlp_scatter<<<grid1, blk, 0, stream>>>(ev, n, mlp_W1, mlp_b1, mlp_W2, mlp_b2,
                                              mlp_W3, mlp_b3, vox, mask, rsum);

    int grid2 = (ROWS + blk - 1) / blk;   // 4050
    row_lstm<<<grid2, blk, 0, stream>>>(mask, rsum, vox, rnn_W1, rnn_b1, W_ih, W_hh,
                                        b_ih, b_hh, rnn_W2, rnn_b2, outp);
}